// Round 1
// baseline (561.836 us; speedup 1.0000x reference)
//
#include <hip/hip_runtime.h>
#include <hip/hip_bf16.h>

#define NPTS 262144
#define DIM  128
#define KC   20
#define MP   10
#define JT   200   // KC*MP
#define LNEPS 1e-5f
#define EPSI  0.05f

// workspace layout (float offsets)
#define WS_PROTON 0          // 25600  normalized prototypes
#define WS_F      25600      // 25600  f accumulator [200][128]
#define WS_NCOUNT 51200      // 200
#define WS_U      51400      // 200    sinkhorn row factors
#define WS_SK     51600      // 20     per-class initial sums
#define WS_BC     51620      // 20     per-class counts
#define WS_PSB    51640      // 40*4096 partials (B rows 0..19, s rows 20..39)
#define WS_PR     215480     // 200*1024 row-sum partials
#define WS_EXPV   420280     // N*10   exp(logit/eps) for own class
#define WS_V      3041720    // N      sinkhorn col factors
#define WS_CORR   3303864    // N      correct flags
// total 3566008 floats = 14.3 MB

// ---- shared helper: load 64 feature rows into swizzled LDS, LayerNorm + l2norm in place
// LDS layout: [64 rows][32 float4 slots], physical slot = s ^ (row&7) (bank-conflict swizzle)
__device__ __forceinline__ void load_and_normalize(
    const float* __restrict__ feat, const float* __restrict__ fg,
    const float* __restrict__ fb, float4* sf4, int base, int t)
{
    const float4* gfeat = (const float4*)feat;
    #pragma unroll
    for (int ii = 0; ii < 8; ++ii) {
        int fid = ii*256 + t;
        int row = fid >> 5, sl = fid & 31;
        sf4[row*32 + (sl ^ (row & 7))] = gfeat[(size_t)(base+row)*32 + sl];
    }
    __syncthreads();
    const int p = t >> 2, sub = t & 3, sw = p & 7;
    float s0 = 0.f;
    #pragma unroll
    for (int q = 0; q < 8; ++q) {
        float4 v = sf4[p*32 + ((sub*8+q) ^ sw)];
        s0 += v.x + v.y + v.z + v.w;
    }
    s0 += __shfl_xor(s0, 1); s0 += __shfl_xor(s0, 2);
    float mean = s0 / 128.f;
    float s1 = 0.f;
    #pragma unroll
    for (int q = 0; q < 8; ++q) {
        float4 v = sf4[p*32 + ((sub*8+q) ^ sw)];
        float a=v.x-mean, b=v.y-mean, c=v.z-mean, d=v.w-mean;
        s1 += a*a + b*b + c*c + d*d;
    }
    s1 += __shfl_xor(s1, 1); s1 += __shfl_xor(s1, 2);
    float rstd = rsqrtf(s1 / 128.f + LNEPS);
    const float4* fg4 = (const float4*)fg;
    const float4* fb4 = (const float4*)fb;
    float s2 = 0.f;
    #pragma unroll
    for (int q = 0; q < 8; ++q) {
        int sl = sub*8+q;
        float4 v = sf4[p*32 + (sl ^ sw)];
        float4 g = fg4[sl], bb = fb4[sl];
        v.x = (v.x-mean)*rstd*g.x + bb.x;
        v.y = (v.y-mean)*rstd*g.y + bb.y;
        v.z = (v.z-mean)*rstd*g.z + bb.z;
        v.w = (v.w-mean)*rstd*g.w + bb.w;
        sf4[p*32 + (sl ^ sw)] = v;
        s2 += v.x*v.x + v.y*v.y + v.z*v.z + v.w*v.w;
    }
    s2 += __shfl_xor(s2, 1); s2 += __shfl_xor(s2, 2);
    float rl2 = 1.f / fmaxf(sqrtf(s2), 1e-12f);
    #pragma unroll
    for (int q = 0; q < 8; ++q) {
        int sl = sub*8+q;
        float4 v = sf4[p*32 + (sl ^ sw)];
        v.x *= rl2; v.y *= rl2; v.z *= rl2; v.w *= rl2;
        sf4[p*32 + (sl ^ sw)] = v;
    }
}

// ---- normalize prototype rows: 200 blocks x 64 (one wave per row)
__global__ __launch_bounds__(64) void k_norm_protos(
    const float* __restrict__ pr, float* __restrict__ pn)
{
    int j = blockIdx.x, l = threadIdx.x;
    float x0 = pr[(size_t)j*128 + l], x1 = pr[(size_t)j*128 + 64 + l];
    float ss = x0*x0 + x1*x1;
    #pragma unroll
    for (int off = 32; off > 0; off >>= 1) ss += __shfl_xor(ss, off);
    float dn = fmaxf(sqrtf(ss), 1e-12f);
    pn[(size_t)j*128 + l]      = x0/dn;
    pn[(size_t)j*128 + 64 + l] = x1/dn;
}

__global__ void k_init_u(float* u) { if (threadIdx.x < 200) u[threadIdx.x] = 1.f; }

// ---- main fused kernel: _c, logits GEMM, out_seg LN, pred/correct, expv, class partials
__global__ __launch_bounds__(256) void k_main(
    const float* __restrict__ feat, const int* __restrict__ gt,
    const float* __restrict__ pn,
    const float* __restrict__ fg, const float* __restrict__ fb,
    const float* __restrict__ mg, const float* __restrict__ mb,
    float* __restrict__ out_seg, float* __restrict__ plog,
    float* __restrict__ expv, float* __restrict__ psb, float* __restrict__ corr)
{
    __shared__ __align__(16) float smem[13312]; // feat 8192 | proto 5120 ; reused as logits [64][200]
    __shared__ float sumexpS[64];
    __shared__ int   gtS[64];
    const int t = threadIdx.x, blk = blockIdx.x, base = blk * 64;
    float4* sf4 = (float4*)smem;
    float4* pf4 = (float4*)(smem + 8192);

    load_and_normalize(feat, fg, fb, sf4, base, t);
    __syncthreads();

    // GEMM: 64 pts x 200 protos, thread tile = 2 pts x 25 protos (5 per chunk x 5 chunks)
    const int pg = t >> 5, ptg = t & 31;
    const int p0 = ptg, p1 = ptg + 32, sw0 = p0 & 7; // (p0+32)&7 == p0&7
    float acc0[25], acc1[25];
    #pragma unroll
    for (int i = 0; i < 25; ++i) { acc0[i] = 0.f; acc1[i] = 0.f; }
    const float4* gpn = (const float4*)pn;
    #pragma unroll
    for (int c = 0; c < 5; ++c) {
        if (c) __syncthreads();
        #pragma unroll
        for (int ii = 0; ii < 5; ++ii) {
            int fid = ii*256 + t;
            int row = fid >> 5, sl = fid & 31;
            pf4[row*32 + (sl ^ (row & 7))] = gpn[(size_t)(c*40+row)*32 + sl];
        }
        __syncthreads();
        #pragma unroll 2
        for (int s = 0; s < 32; ++s) {
            float4 a0 = sf4[p0*32 + (s ^ sw0)];
            float4 a1 = sf4[p1*32 + (s ^ sw0)];
            #pragma unroll
            for (int jj = 0; jj < 5; ++jj) {
                int lr = pg*5 + jj;
                float4 b = pf4[lr*32 + (s ^ (lr & 7))];
                acc0[c*5+jj] += a0.x*b.x + a0.y*b.y + a0.z*b.z + a0.w*b.w;
                acc1[c*5+jj] += a1.x*b.x + a1.y*b.y + a1.z*b.z + a1.w*b.w;
            }
        }
    }
    __syncthreads();
    // stage logits to LDS [64][200]
    #pragma unroll
    for (int c = 0; c < 5; ++c)
        #pragma unroll
        for (int jj = 0; jj < 5; ++jj) {
            int jglob = c*40 + pg*5 + jj;
            smem[p0*200 + jglob] = acc0[c*5+jj];
            smem[p1*200 + jglob] = acc1[c*5+jj];
        }
    __syncthreads();
    // coalesced logits write
    {
        size_t ob = (size_t)base * 200;
        for (int ii = 0; ii < 50; ++ii)
            plog[ob + ii*256 + t] = smem[ii*256 + t];
    }
    // per-point epilogue: 4 lanes per point, 5 classes each
    {
        const int p = t >> 2, sub = t & 3;
        const int n = base + p;
        float ml[5];
        #pragma unroll
        for (int kk = 0; kk < 5; ++kk) {
            int k = sub*5 + kk;
            float mx = smem[p*200 + k*10];
            #pragma unroll
            for (int m = 1; m < 10; ++m) mx = fmaxf(mx, smem[p*200 + k*10 + m]);
            ml[kk] = mx;
        }
        float s0 = ml[0]+ml[1]+ml[2]+ml[3]+ml[4];
        s0 += __shfl_xor(s0,1); s0 += __shfl_xor(s0,2);
        float mean = s0 / 20.f;
        float s1 = 0.f;
        #pragma unroll
        for (int kk = 0; kk < 5; ++kk) { float d = ml[kk]-mean; s1 += d*d; }
        s1 += __shfl_xor(s1,1); s1 += __shfl_xor(s1,2);
        float rstd = rsqrtf(s1 / 20.f + LNEPS);
        float bv = -1e30f; int bk = 0;
        #pragma unroll
        for (int kk = 0; kk < 5; ++kk) {
            int k = sub*5 + kk;
            float y = (ml[kk]-mean)*rstd*mg[k] + mb[k];
            out_seg[(size_t)n*20 + k] = y;
            if (y > bv) { bv = y; bk = k; }
        }
        #pragma unroll
        for (int off = 1; off <= 2; off <<= 1) {   // first-max-wins merge
            float ov = __shfl_xor(bv, off);
            int   ok = __shfl_xor(bk, off);
            if (ov > bv || (ov == bv && ok < bk)) { bv = ov; bk = ok; }
        }
        int g = gt[n];
        if (sub == 0) {
            corr[n] = (bk == g) ? 1.f : 0.f;
            float se = 0.f;
            #pragma unroll
            for (int m = 0; m < 10; ++m) {
                float e = expf(smem[p*200 + g*10 + m] / EPSI);
                expv[(size_t)n*10 + m] = e;
                se += e;
            }
            sumexpS[p] = se;
            gtS[p] = g;
        }
    }
    __syncthreads();
    // deterministic per-block class partials (count + expv-sum)
    if (t < 20) {
        float cnt = 0.f, s = 0.f;
        for (int p = 0; p < 64; ++p)
            if (gtS[p] == t) { cnt += 1.f; s += sumexpS[p]; }
        psb[(size_t)t*4096 + blk]      = cnt;
        psb[(size_t)(20+t)*4096 + blk] = s;
    }
}

// ---- reduce class partials -> Bc, sk (deterministic tree)
__global__ __launch_bounds__(256) void k_reduce_sB(
    const float* __restrict__ psb, float* __restrict__ sk, float* __restrict__ Bc)
{
    __shared__ float red[256];
    int t = threadIdx.x, r = blockIdx.x;
    float s = 0.f;
    for (int i = 0; i < 16; ++i) s += psb[(size_t)r*4096 + i*256 + t];
    red[t] = s; __syncthreads();
    for (int off = 128; off > 0; off >>= 1) { if (t < off) red[t] += red[t+off]; __syncthreads(); }
    if (t == 0) { if (r < 20) Bc[r] = red[0]; else sk[r-20] = red[0]; }
}

__global__ void k_init_v(const int* __restrict__ gt, const float* __restrict__ sk,
                         float* __restrict__ v)
{
    int n = blockIdx.x*256 + threadIdx.x;
    float s = sk[gt[n]];
    v[n] = (s > 0.f) ? 1.f/s : 1.f;
}

// ---- sinkhorn row pass: per-block deterministic partial row sums
__global__ __launch_bounds__(256) void k_row(const int* __restrict__ gt,
    const float* __restrict__ expv, const float* __restrict__ v, float* __restrict__ pr)
{
    __shared__ float prodS[256*10];
    __shared__ int gtS[256];
    int t = threadIdx.x, b = blockIdx.x;
    int n = b*256 + t;
    int k = gt[n];
    float vv = v[n];
    #pragma unroll
    for (int m = 0; m < 10; ++m) prodS[t*10+m] = expv[(size_t)n*10+m]*vv;
    gtS[t] = k;
    __syncthreads();
    if (t < 200) {
        int kk = t / 10, mm = t % 10;
        float acc = 0.f;
        for (int i = 0; i < 256; ++i)
            if (gtS[i] == kk) acc += prodS[i*10+mm];
        pr[(size_t)t*1024 + b] = acc;
    }
}

// ---- row partials -> u update (with faithful rs>0 guard), deterministic
__global__ __launch_bounds__(256) void k_reduce_u(const float* __restrict__ pr, float* __restrict__ u)
{
    __shared__ float red[256];
    int t = threadIdx.x, j = blockIdx.x;
    float s = 0.f;
    #pragma unroll
    for (int i = 0; i < 4; ++i) s += pr[(size_t)j*1024 + i*256 + t];
    red[t] = s; __syncthreads();
    for (int off = 128; off > 0; off >>= 1) { if (t < off) red[t] += red[t+off]; __syncthreads(); }
    if (t == 0) {
        float S = red[0], uold = u[j];
        u[j] = (S > 0.f) ? 1.f/(10.f*S) : uold*(1.f/10.f);
    }
}

// ---- sinkhorn col pass (pointwise)
__global__ void k_col(const int* __restrict__ gt, const float* __restrict__ expv,
                      const float* __restrict__ u, const float* __restrict__ Bc,
                      float* __restrict__ v)
{
    int n = blockIdx.x*256 + threadIdx.x;
    int k = gt[n];
    const float* uk = u + k*10;
    float sc = 0.f;
    #pragma unroll
    for (int m = 0; m < 10; ++m) sc += expv[(size_t)n*10+m]*uk[m];
    float B = Bc[k];
    float Bs = (B > 0.f) ? B : 1.f;
    float vo = v[n];
    v[n] = (sc > 0.f) ? 1.f/(Bs*sc) : vo/Bs;
}

// ---- finalize: per-point proto assignment, proto_target, f/ncount accumulation
__global__ __launch_bounds__(256) void k_finalize(
    const float* __restrict__ feat, const int* __restrict__ gt,
    const float* __restrict__ fg, const float* __restrict__ fb,
    const float* __restrict__ expv, const float* __restrict__ u,
    const float* __restrict__ corr,
    float* __restrict__ ptarget, float* __restrict__ facc, float* __restrict__ ncount)
{
    __shared__ __align__(16) float smem[8192];
    const int t = threadIdx.x, base = blockIdx.x * 64;
    float4* sf4 = (float4*)smem;
    load_and_normalize(feat, fg, fb, sf4, base, t);  // recompute _c (bit-identical to k_main)

    const int p = t >> 2, sub = t & 3;
    const int n = base + p;
    int g = 0, idx = 0; float cr = 0.f;
    if (sub == 0) {
        g = gt[n];
        cr = corr[n];
        const float* uk = u + g*10;
        float bv = -1e30f;
        #pragma unroll
        for (int m = 0; m < 10; ++m) {
            float pm = expv[(size_t)n*10+m] * uk[m];
            if (pm > bv) { bv = pm; idx = m; }
        }
        ptarget[n] = (float)(idx + 10*g);
        if (cr != 0.f) atomicAdd(&ncount[g*10+idx], 1.f);
    }
    int lb = t & ~3;
    g   = __shfl(g, lb);
    idx = __shfl(idx, lb);
    cr  = __shfl(cr, lb);
    if (cr != 0.f) {
        float* frow = facc + (size_t)(g*10+idx)*128;
        const int sw = p & 7;
        #pragma unroll
        for (int q = 0; q < 8; ++q) {
            int sl = sub*8+q;
            float4 v = sf4[p*32 + (sl ^ sw)];
            atomicAdd(&frow[sl*4+0], v.x);
            atomicAdd(&frow[sl*4+1], v.y);
            atomicAdd(&frow[sl*4+2], v.z);
            atomicAdd(&frow[sl*4+3], v.w);
        }
    }
}

// ---- momentum update + renormalize prototypes
__global__ __launch_bounds__(64) void k_proto_update(
    const float* __restrict__ facc, const float* __restrict__ ncount,
    const float* __restrict__ pn, float* __restrict__ outp)
{
    const float OMG = (float)(1.0 - 0.99);
    int j = blockIdx.x, l = threadIdx.x;
    float f0 = facc[(size_t)j*128+l], f1 = facc[(size_t)j*128+64+l];
    float ss = f0*f0 + f1*f1;
    #pragma unroll
    for (int off = 32; off > 0; off >>= 1) ss += __shfl_xor(ss, off);
    float fl2 = fmaxf(sqrtf(ss), 1e-12f);
    float fn0 = f0/fl2, fn1 = f1/fl2;
    float p0 = pn[(size_t)j*128+l], p1 = pn[(size_t)j*128+64+l];
    float u0 = 0.99f*p0 + OMG*fn0, u1 = 0.99f*p1 + OMG*fn1;
    bool ok = ncount[j] > 0.f;
    float s0 = ok ? u0 : p0, s1 = ok ? u1 : p1;
    float ss2 = s0*s0 + s1*s1;
    #pragma unroll
    for (int off = 32; off > 0; off >>= 1) ss2 += __shfl_xor(ss2, off);
    float l2 = fmaxf(sqrtf(ss2), 1e-12f);
    outp[(size_t)j*128+l]      = s0/l2;
    outp[(size_t)j*128+64+l]   = s1/l2;
}

extern "C" void kernel_launch(void* const* d_in, const int* in_sizes, int n_in,
                              void* d_out, int out_size, void* d_ws, size_t ws_size,
                              hipStream_t stream)
{
    const float* feat   = (const float*)d_in[0];
    const int*   gt     = (const int*)  d_in[1];
    const float* protos = (const float*)d_in[2];
    const float* fg     = (const float*)d_in[3];
    const float* fb     = (const float*)d_in[4];
    const float* mg     = (const float*)d_in[5];
    const float* mb     = (const float*)d_in[6];

    float* out      = (float*)d_out;
    float* out_seg  = out;
    float* plog     = out + (size_t)NPTS*20;
    float* ptarget  = out + (size_t)NPTS*220;
    float* newp     = out + (size_t)NPTS*221;

    float* ws   = (float*)d_ws;
    float* pn   = ws + WS_PROTON;
    float* facc = ws + WS_F;
    float* ncnt = ws + WS_NCOUNT;
    float* u    = ws + WS_U;
    float* sk   = ws + WS_SK;
    float* Bc   = ws + WS_BC;
    float* psb  = ws + WS_PSB;
    float* pr   = ws + WS_PR;
    float* expv = ws + WS_EXPV;
    float* v    = ws + WS_V;
    float* corr = ws + WS_CORR;

    // zero f + ncount (contiguous), set u = 1
    hipMemsetAsync(facc, 0, (25600 + 200)*sizeof(float), stream);
    hipLaunchKernelGGL(k_init_u, dim3(1), dim3(256), 0, stream, u);
    hipLaunchKernelGGL(k_norm_protos, dim3(200), dim3(64), 0, stream, protos, pn);
    hipLaunchKernelGGL(k_main, dim3(4096), dim3(256), 0, stream,
                       feat, gt, pn, fg, fb, mg, mb, out_seg, plog, expv, psb, corr);
    hipLaunchKernelGGL(k_reduce_sB, dim3(40), dim3(256), 0, stream, psb, sk, Bc);
    hipLaunchKernelGGL(k_init_v, dim3(1024), dim3(256), 0, stream, gt, sk, v);
    for (int it = 0; it < 3; ++it) {
        hipLaunchKernelGGL(k_row, dim3(1024), dim3(256), 0, stream, gt, expv, v, pr);
        hipLaunchKernelGGL(k_reduce_u, dim3(200), dim3(256), 0, stream, pr, u);
        if (it < 2)
            hipLaunchKernelGGL(k_col, dim3(1024), dim3(256), 0, stream, gt, expv, u, Bc, v);
    }
    hipLaunchKernelGGL(k_finalize, dim3(4096), dim3(256), 0, stream,
                       feat, gt, fg, fb, expv, u, corr, ptarget, facc, ncnt);
    hipLaunchKernelGGL(k_proto_update, dim3(200), dim3(64), 0, stream, facc, ncnt, pn, newp);
}

// Round 2
// 430.373 us; speedup vs baseline: 1.3055x; 1.3055x over previous
//
#include <hip/hip_runtime.h>
#include <hip/hip_bf16.h>

#define NPTS 262144
#define DIM  128
#define KC   20
#define MP   10
#define LNEPS 1e-5f
#define EPSI  0.05f

typedef _Float16 half8 __attribute__((ext_vector_type(8)));
typedef float f32x4 __attribute__((ext_vector_type(4)));

union H8U4 { half8 h; uint4 u; };

// workspace layout (float offsets)
#define WS_PN     0          // 25600 normalized protos f32
#define WS_PHI    25600      // 13312 floats = 26624 halfs (208x128 f16 hi)
#define WS_PLO    38912      // 13312 floats (f16 lo)
#define WS_F      52224      // 25600 f accumulator
#define WS_NCOUNT 77824      // 200
#define WS_UH     78024      // 600 u history (3 x 200)
#define WS_SK     78624      // 20
#define WS_BC     78644      // 20
#define WS_PSB    78664      // 40*2048
#define WS_PR     160584     // 200*1024
#define WS_EXPV   365384     // N*12 (10 + 2 pad)
#define WS_CORR   3511112    // N
// total 3773256 floats = 15.1 MB

__device__ __forceinline__ half8 lds_h8(const uint4* p) {
    return *reinterpret_cast<const half8*>(p);
}

// ---- normalize prototypes, emit f32 + f16 hi/lo (rows 200..207 zero-padded)
__global__ __launch_bounds__(64) void k_norm_protos(
    const float* __restrict__ pr, float* __restrict__ pn,
    _Float16* __restrict__ phi, _Float16* __restrict__ plo)
{
    int j = blockIdx.x, l = threadIdx.x;
    if (j < 200) {
        float x0 = pr[(size_t)j*128 + l], x1 = pr[(size_t)j*128 + 64 + l];
        float ss = x0*x0 + x1*x1;
        #pragma unroll
        for (int off = 32; off > 0; off >>= 1) ss += __shfl_xor(ss, off);
        float dn = fmaxf(sqrtf(ss), 1e-12f);
        float y0 = x0/dn, y1 = x1/dn;
        pn[(size_t)j*128 + l]      = y0;
        pn[(size_t)j*128 + 64 + l] = y1;
        _Float16 h0 = (_Float16)y0, h1 = (_Float16)y1;
        phi[(size_t)j*128 + l]      = h0;
        phi[(size_t)j*128 + 64 + l] = h1;
        plo[(size_t)j*128 + l]      = (_Float16)(y0 - (float)h0);
        plo[(size_t)j*128 + 64 + l] = (_Float16)(y1 - (float)h1);
    } else {
        phi[(size_t)j*128 + l] = (_Float16)0.f;  phi[(size_t)j*128 + 64 + l] = (_Float16)0.f;
        plo[(size_t)j*128 + l] = (_Float16)0.f;  plo[(size_t)j*128 + 64 + l] = (_Float16)0.f;
    }
}

// ---- main fused kernel: _c (LN+l2n), MFMA hi/lo GEMM, plog, out_seg LN, pred/correct,
//      expv, per-block class partials. Block = 128 points, 4 waves.
__global__ __launch_bounds__(256, 2) void k_main(
    const float* __restrict__ feat, const int* __restrict__ gt,
    const _Float16* __restrict__ phi, const _Float16* __restrict__ plo,
    const float* __restrict__ fg, const float* __restrict__ fb,
    const float* __restrict__ mg, const float* __restrict__ mb,
    float* __restrict__ out_seg, float* __restrict__ plog,
    float* __restrict__ expv, float* __restrict__ psb, float* __restrict__ corr)
{
    __shared__ __align__(16) char smemraw[65536];
    __shared__ float sumS[128];
    __shared__ int   gtS[128];
    float4* sf4 = (float4*)smemraw;               // [128][32] f32 staging (slot^(row&15))
    uint4*  aHi = (uint4*)smemraw;                // [128][16] f16 hi (slot^(row&15))
    uint4*  aLo = (uint4*)(smemraw + 32768);      // [128][16] f16 lo
    float*  llds = (float*)smemraw;               // [64][210] logits staging (epilogue)

    const int t = threadIdx.x, blk = blockIdx.x;
    const int w = t >> 6, lane = t & 63;

    // ---- stage feat f32 (coalesced)
    {
        const float4* gfeat = (const float4*)feat + (size_t)blk*4096;
        #pragma unroll
        for (int ii = 0; ii < 16; ++ii) {
            int idx = ii*256 + t, row = idx >> 5, s = idx & 31;
            sf4[row*32 + (s ^ (row & 15))] = gfeat[idx];
        }
    }
    __syncthreads();

    // ---- LayerNorm + l2n, 2 threads/row, result kept in regs
    const int p = t >> 1, hsub = t & 1, sw = p & 15;
    float4 r[16];
    {
        float s0 = 0.f;
        #pragma unroll
        for (int q = 0; q < 16; ++q) {
            float4 v = sf4[p*32 + ((hsub*16 + q) ^ sw)];
            s0 += v.x + v.y + v.z + v.w;
        }
        s0 += __shfl_xor(s0, 1);
        float mean = s0 * (1.f/128.f);
        float s1 = 0.f;
        #pragma unroll
        for (int q = 0; q < 16; ++q) {
            float4 v = sf4[p*32 + ((hsub*16 + q) ^ sw)];
            float a = v.x-mean, b = v.y-mean, c = v.z-mean, d = v.w-mean;
            s1 += a*a + b*b + c*c + d*d;
        }
        s1 += __shfl_xor(s1, 1);
        float rstd = rsqrtf(s1 * (1.f/128.f) + LNEPS);
        const float4* fg4 = (const float4*)fg;
        const float4* fb4 = (const float4*)fb;
        float s2 = 0.f;
        #pragma unroll
        for (int q = 0; q < 16; ++q) {
            int sl = hsub*16 + q;
            float4 v = sf4[p*32 + (sl ^ sw)];
            float4 g = fg4[sl], bb = fb4[sl];
            v.x = (v.x-mean)*rstd*g.x + bb.x;
            v.y = (v.y-mean)*rstd*g.y + bb.y;
            v.z = (v.z-mean)*rstd*g.z + bb.z;
            v.w = (v.w-mean)*rstd*g.w + bb.w;
            r[q] = v;
            s2 += v.x*v.x + v.y*v.y + v.z*v.z + v.w*v.w;
        }
        s2 += __shfl_xor(s2, 1);
        float rl2 = 1.f / fmaxf(sqrtf(s2), 1e-12f);
        #pragma unroll
        for (int q = 0; q < 16; ++q) { r[q].x *= rl2; r[q].y *= rl2; r[q].z *= rl2; r[q].w *= rl2; }
    }
    __syncthreads();   // all f32 reads complete before overwriting with f16

    // ---- convert to f16 hi/lo, write swizzled LDS
    #pragma unroll
    for (int q = 0; q < 8; ++q) {
        float4 va = r[2*q], vb = r[2*q+1];
        H8U4 h, lo;
        h.h[0]=(_Float16)va.x; h.h[1]=(_Float16)va.y; h.h[2]=(_Float16)va.z; h.h[3]=(_Float16)va.w;
        h.h[4]=(_Float16)vb.x; h.h[5]=(_Float16)vb.y; h.h[6]=(_Float16)vb.z; h.h[7]=(_Float16)vb.w;
        lo.h[0]=(_Float16)(va.x-(float)h.h[0]); lo.h[1]=(_Float16)(va.y-(float)h.h[1]);
        lo.h[2]=(_Float16)(va.z-(float)h.h[2]); lo.h[3]=(_Float16)(va.w-(float)h.h[3]);
        lo.h[4]=(_Float16)(vb.x-(float)h.h[4]); lo.h[5]=(_Float16)(vb.y-(float)h.h[5]);
        lo.h[6]=(_Float16)(vb.z-(float)h.h[6]); lo.h[7]=(_Float16)(vb.w-(float)h.h[7]);
        int slot = hsub*8 + q;
        aHi[p*16 + (slot ^ sw)] = h.u;
        aLo[p*16 + (slot ^ sw)] = lo.u;
    }
    __syncthreads();

    // ---- MFMA main loop: wave w -> points w*32..w*32+31, 13 N-tiles, 4 K-steps
    const int l15 = lane & 15, l4 = lane >> 4;
    f32x4 acc[2][13];
    #pragma unroll
    for (int mt = 0; mt < 2; ++mt)
        #pragma unroll
        for (int nt = 0; nt < 13; ++nt)
            acc[mt][nt] = (f32x4){0.f,0.f,0.f,0.f};

    const int arow0 = w*32 + l15;
    const _Float16* phiL = phi + l15*128 + l4*8;
    const _Float16* ploL = plo + l15*128 + l4*8;

    #pragma unroll
    for (int kst = 0; kst < 4; ++kst) {
        const int sl = (kst*4 + l4) ^ l15;   // row&15 == l15 for both M-tiles
        half8 a0h = lds_h8(&aHi[arow0*16 + sl]);
        half8 a0l = lds_h8(&aLo[arow0*16 + sl]);
        half8 a1h = lds_h8(&aHi[(arow0+16)*16 + sl]);
        half8 a1l = lds_h8(&aLo[(arow0+16)*16 + sl]);
        #pragma unroll
        for (int nt = 0; nt < 13; ++nt) {
            half8 bh = *reinterpret_cast<const half8*>(phiL + nt*2048 + kst*32);
            half8 bl = *reinterpret_cast<const half8*>(ploL + nt*2048 + kst*32);
            acc[0][nt] = __builtin_amdgcn_mfma_f32_16x16x32_f16(a0h, bh, acc[0][nt], 0,0,0);
            acc[0][nt] = __builtin_amdgcn_mfma_f32_16x16x32_f16(a0l, bh, acc[0][nt], 0,0,0);
            acc[0][nt] = __builtin_amdgcn_mfma_f32_16x16x32_f16(a0h, bl, acc[0][nt], 0,0,0);
            acc[0][nt] = __builtin_amdgcn_mfma_f32_16x16x32_f16(a0l, bl, acc[0][nt], 0,0,0);
            acc[1][nt] = __builtin_amdgcn_mfma_f32_16x16x32_f16(a1h, bh, acc[1][nt], 0,0,0);
            acc[1][nt] = __builtin_amdgcn_mfma_f32_16x16x32_f16(a1l, bh, acc[1][nt], 0,0,0);
            acc[1][nt] = __builtin_amdgcn_mfma_f32_16x16x32_f16(a1h, bl, acc[1][nt], 0,0,0);
            acc[1][nt] = __builtin_amdgcn_mfma_f32_16x16x32_f16(a1l, bl, acc[1][nt], 0,0,0);
        }
    }

    // ---- write plog directly from acc (64B segments per quarter-wave)
    #pragma unroll
    for (int mt = 0; mt < 2; ++mt)
        #pragma unroll
        for (int nt = 0; nt < 13; ++nt)
            #pragma unroll
            for (int rr = 0; rr < 4; ++rr)
                if (nt < 12 || l15 < 8)
                    plog[(size_t)(blk*128 + w*32 + mt*16 + l4*4 + rr)*200 + nt*16 + l15]
                        = acc[mt][nt][rr];

    // ---- two-pass epilogue via LDS logits staging (reuses A region)
    #pragma unroll
    for (int pass = 0; pass < 2; ++pass) {
        __syncthreads();   // A arrays dead / previous pass reads done
        #pragma unroll
        for (int nt = 0; nt < 13; ++nt)
            #pragma unroll
            for (int rr = 0; rr < 4; ++rr) {
                int row = w*16 + l4*4 + rr;
                int col = nt*16 + l15;
                if (col < 200) llds[row*210 + col] = acc[pass][nt][rr];
            }
        __syncthreads();
        // epilogue: 4 lanes per point, 5 classes each
        const int q = t >> 2, sub = t & 3;
        const int bp = (q >> 4)*32 + pass*16 + (q & 15);   // block-local point
        const int n = blk*128 + bp;
        float ml[5];
        #pragma unroll
        for (int kk = 0; kk < 5; ++kk) {
            int k = sub*5 + kk;
            float mx = llds[q*210 + k*10];
            #pragma unroll
            for (int m = 1; m < 10; ++m) mx = fmaxf(mx, llds[q*210 + k*10 + m]);
            ml[kk] = mx;
        }
        float s0 = ml[0]+ml[1]+ml[2]+ml[3]+ml[4];
        s0 += __shfl_xor(s0,1); s0 += __shfl_xor(s0,2);
        float mean = s0 / 20.f;
        float s1 = 0.f;
        #pragma unroll
        for (int kk = 0; kk < 5; ++kk) { float d = ml[kk]-mean; s1 += d*d; }
        s1 += __shfl_xor(s1,1); s1 += __shfl_xor(s1,2);
        float rstd = rsqrtf(s1 / 20.f + LNEPS);
        float bv = -1e30f; int bk = 0;
        #pragma unroll
        for (int kk = 0; kk < 5; ++kk) {
            int k = sub*5 + kk;
            float y = (ml[kk]-mean)*rstd*mg[k] + mb[k];
            out_seg[(size_t)n*20 + k] = y;
            if (y > bv) { bv = y; bk = k; }
        }
        #pragma unroll
        for (int off = 1; off <= 2; off <<= 1) {   // first-max-wins merge
            float ov = __shfl_xor(bv, off);
            int   ok = __shfl_xor(bk, off);
            if (ov > bv || (ov == bv && ok < bk)) { bv = ov; bk = ok; }
        }
        int g = gt[n];
        if (sub == 0) {
            corr[n] = (bk == g) ? 1.f : 0.f;
            float se = 0.f;
            #pragma unroll
            for (int m = 0; m < 10; ++m) {
                float e = expf(llds[q*210 + g*10 + m] / EPSI);
                expv[(size_t)n*12 + m] = e;
                se += e;
            }
            expv[(size_t)n*12 + 10] = 0.f;
            expv[(size_t)n*12 + 11] = 0.f;
            sumS[pass*64 + q] = se;
            gtS[pass*64 + q] = g;
        }
    }
    __syncthreads();
    // ---- deterministic per-block class partials
    if (t < 20) {
        float cnt = 0.f, s = 0.f;
        for (int i = 0; i < 128; ++i)
            if (gtS[i] == t) { cnt += 1.f; s += sumS[i]; }
        psb[(size_t)t*2048 + blk]      = cnt;
        psb[(size_t)(20+t)*2048 + blk] = s;
    }
}

// ---- reduce class partials -> Bc, sk (deterministic tree)
__global__ __launch_bounds__(256) void k_reduce_sB(
    const float* __restrict__ psb, float* __restrict__ sk, float* __restrict__ Bc)
{
    __shared__ float red[256];
    int t = threadIdx.x, rrow = blockIdx.x;
    float s = 0.f;
    #pragma unroll
    for (int i = 0; i < 8; ++i) s += psb[(size_t)rrow*2048 + i*256 + t];
    red[t] = s; __syncthreads();
    for (int off = 128; off > 0; off >>= 1) { if (t < off) red[t] += red[t+off]; __syncthreads(); }
    if (t == 0) { if (rrow < 20) Bc[rrow] = red[0]; else sk[rrow-20] = red[0]; }
}

// ---- sinkhorn row pass with fused v-chain (iter = 1,2,3)
__global__ __launch_bounds__(256) void k_row(int iter,
    const int* __restrict__ gt, const float* __restrict__ expv,
    const float* __restrict__ uh, const float* __restrict__ sk,
    const float* __restrict__ Bc, float* __restrict__ pr)
{
    __shared__ float prodS[256*10];
    __shared__ int gtS[256];
    int t = threadIdx.x, b = blockIdx.x;
    int n = b*256 + t;
    int g = gt[n];
    float e[10];
    {
        const float4* e4 = (const float4*)(expv + (size_t)n*12);
        float4 ea = e4[0], eb = e4[1], ec = e4[2];
        e[0]=ea.x; e[1]=ea.y; e[2]=ea.z; e[3]=ea.w;
        e[4]=eb.x; e[5]=eb.y; e[6]=eb.z; e[7]=eb.w;
        e[8]=ec.x; e[9]=ec.y;
    }
    float skg = sk[g];
    float v = (skg > 0.f) ? 1.f/skg : 1.f;
    float B = Bc[g];
    float Bs = (B > 0.f) ? B : 1.f;
    for (int c = 1; c < iter; ++c) {
        const float* uc = uh + (c-1)*200 + g*10;
        float sc = 0.f;
        #pragma unroll
        for (int m = 0; m < 10; ++m) sc += e[m]*uc[m];
        v = (sc > 0.f) ? 1.f/(Bs*sc) : v/Bs;
    }
    #pragma unroll
    for (int m = 0; m < 10; ++m) prodS[t*10+m] = e[m]*v;
    gtS[t] = g;
    __syncthreads();
    if (t < 200) {
        int kk = t / 10, mm = t % 10;
        float acc = 0.f;
        for (int i = 0; i < 256; ++i)
            if (gtS[i] == kk) acc += prodS[i*10+mm];
        pr[(size_t)t*1024 + b] = acc;
    }
}

// ---- row partials -> u_hist[iter] (faithful rs>0 guard), deterministic
__global__ __launch_bounds__(256) void k_reduce_u(int iter,
    const float* __restrict__ pr, float* __restrict__ uh)
{
    __shared__ float red[256];
    int t = threadIdx.x, j = blockIdx.x;
    float s = 0.f;
    #pragma unroll
    for (int i = 0; i < 4; ++i) s += pr[(size_t)j*1024 + i*256 + t];
    red[t] = s; __syncthreads();
    for (int off = 128; off > 0; off >>= 1) { if (t < off) red[t] += red[t+off]; __syncthreads(); }
    if (t == 0) {
        float S = red[0];
        float uprev = (iter == 1) ? 1.f : uh[(iter-2)*200 + j];
        uh[(iter-1)*200 + j] = (S > 0.f) ? 1.f/(10.f*S) : uprev*0.1f;
    }
}

// ---- shared helper for k_finalize (round-1 verified): 64 rows, LN+l2n in LDS
__device__ __forceinline__ void load_and_normalize(
    const float* __restrict__ feat, const float* __restrict__ fg,
    const float* __restrict__ fb, float4* sf4, int base, int t)
{
    const float4* gfeat = (const float4*)feat;
    #pragma unroll
    for (int ii = 0; ii < 8; ++ii) {
        int fid = ii*256 + t;
        int row = fid >> 5, sl = fid & 31;
        sf4[row*32 + (sl ^ (row & 7))] = gfeat[(size_t)(base+row)*32 + sl];
    }
    __syncthreads();
    const int p = t >> 2, sub = t & 3, sw = p & 7;
    float s0 = 0.f;
    #pragma unroll
    for (int q = 0; q < 8; ++q) {
        float4 v = sf4[p*32 + ((sub*8+q) ^ sw)];
        s0 += v.x + v.y + v.z + v.w;
    }
    s0 += __shfl_xor(s0, 1); s0 += __shfl_xor(s0, 2);
    float mean = s0 / 128.f;
    float s1 = 0.f;
    #pragma unroll
    for (int q = 0; q < 8; ++q) {
        float4 v = sf4[p*32 + ((sub*8+q) ^ sw)];
        float a=v.x-mean, b=v.y-mean, c=v.z-mean, d=v.w-mean;
        s1 += a*a + b*b + c*c + d*d;
    }
    s1 += __shfl_xor(s1, 1); s1 += __shfl_xor(s1, 2);
    float rstd = rsqrtf(s1 / 128.f + LNEPS);
    const float4* fg4 = (const float4*)fg;
    const float4* fb4 = (const float4*)fb;
    float s2 = 0.f;
    #pragma unroll
    for (int q = 0; q < 8; ++q) {
        int sl = sub*8+q;
        float4 v = sf4[p*32 + (sl ^ sw)];
        float4 g = fg4[sl], bb = fb4[sl];
        v.x = (v.x-mean)*rstd*g.x + bb.x;
        v.y = (v.y-mean)*rstd*g.y + bb.y;
        v.z = (v.z-mean)*rstd*g.z + bb.z;
        v.w = (v.w-mean)*rstd*g.w + bb.w;
        sf4[p*32 + (sl ^ sw)] = v;
        s2 += v.x*v.x + v.y*v.y + v.z*v.z + v.w*v.w;
    }
    s2 += __shfl_xor(s2, 1); s2 += __shfl_xor(s2, 2);
    float rl2 = 1.f / fmaxf(sqrtf(s2), 1e-12f);
    #pragma unroll
    for (int q = 0; q < 8; ++q) {
        int sl = sub*8+q;
        float4 v = sf4[p*32 + (sl ^ sw)];
        v.x *= rl2; v.y *= rl2; v.z *= rl2; v.w *= rl2;
        sf4[p*32 + (sl ^ sw)] = v;
    }
}

// ---- finalize: per-point proto assignment, proto_target, f/ncount accumulation
__global__ __launch_bounds__(256) void k_finalize(
    const float* __restrict__ feat, const int* __restrict__ gt,
    const float* __restrict__ fg, const float* __restrict__ fb,
    const float* __restrict__ expv, const float* __restrict__ u,
    const float* __restrict__ corr,
    float* __restrict__ ptarget, float* __restrict__ facc, float* __restrict__ ncount)
{
    __shared__ __align__(16) float smem[8192];
    const int t = threadIdx.x, base = blockIdx.x * 64;
    float4* sf4 = (float4*)smem;
    load_and_normalize(feat, fg, fb, sf4, base, t);

    const int p = t >> 2, sub = t & 3;
    const int n = base + p;
    int g = 0, idx = 0; float cr = 0.f;
    if (sub == 0) {
        g = gt[n];
        cr = corr[n];
        const float* uk = u + g*10;
        float bv = -1e30f;
        #pragma unroll
        for (int m = 0; m < 10; ++m) {
            float pm = expv[(size_t)n*12+m] * uk[m];
            if (pm > bv) { bv = pm; idx = m; }
        }
        ptarget[n] = (float)(idx + 10*g);
        if (cr != 0.f) atomicAdd(&ncount[g*10+idx], 1.f);
    }
    int lb = t & ~3;
    g   = __shfl(g, lb);
    idx = __shfl(idx, lb);
    cr  = __shfl(cr, lb);
    if (cr != 0.f) {
        float* frow = facc + (size_t)(g*10+idx)*128;
        const int sw = p & 7;
        #pragma unroll
        for (int q = 0; q < 8; ++q) {
            int sl = sub*8+q;
            float4 v = sf4[p*32 + (sl ^ sw)];
            atomicAdd(&frow[sl*4+0], v.x);
            atomicAdd(&frow[sl*4+1], v.y);
            atomicAdd(&frow[sl*4+2], v.z);
            atomicAdd(&frow[sl*4+3], v.w);
        }
    }
}

// ---- momentum update + renormalize prototypes
__global__ __launch_bounds__(64) void k_proto_update(
    const float* __restrict__ facc, const float* __restrict__ ncount,
    const float* __restrict__ pn, float* __restrict__ outp)
{
    const float OMG = (float)(1.0 - 0.99);
    int j = blockIdx.x, l = threadIdx.x;
    float f0 = facc[(size_t)j*128+l], f1 = facc[(size_t)j*128+64+l];
    float ss = f0*f0 + f1*f1;
    #pragma unroll
    for (int off = 32; off > 0; off >>= 1) ss += __shfl_xor(ss, off);
    float fl2 = fmaxf(sqrtf(ss), 1e-12f);
    float fn0 = f0/fl2, fn1 = f1/fl2;
    float p0 = pn[(size_t)j*128+l], p1 = pn[(size_t)j*128+64+l];
    float u0 = 0.99f*p0 + OMG*fn0, u1 = 0.99f*p1 + OMG*fn1;
    bool ok = ncount[j] > 0.f;
    float s0 = ok ? u0 : p0, s1 = ok ? u1 : p1;
    float ss2 = s0*s0 + s1*s1;
    #pragma unroll
    for (int off = 32; off > 0; off >>= 1) ss2 += __shfl_xor(ss2, off);
    float l2 = fmaxf(sqrtf(ss2), 1e-12f);
    outp[(size_t)j*128+l]      = s0/l2;
    outp[(size_t)j*128+64+l]   = s1/l2;
}

extern "C" void kernel_launch(void* const* d_in, const int* in_sizes, int n_in,
                              void* d_out, int out_size, void* d_ws, size_t ws_size,
                              hipStream_t stream)
{
    const float* feat   = (const float*)d_in[0];
    const int*   gt     = (const int*)  d_in[1];
    const float* protos = (const float*)d_in[2];
    const float* fg     = (const float*)d_in[3];
    const float* fb     = (const float*)d_in[4];
    const float* mg     = (const float*)d_in[5];
    const float* mb     = (const float*)d_in[6];

    float* out      = (float*)d_out;
    float* out_seg  = out;
    float* plog     = out + (size_t)NPTS*20;
    float* ptarget  = out + (size_t)NPTS*220;
    float* newp     = out + (size_t)NPTS*221;

    float* ws   = (float*)d_ws;
    float* pn   = ws + WS_PN;
    _Float16* phi = (_Float16*)(ws + WS_PHI);
    _Float16* plo = (_Float16*)(ws + WS_PLO);
    float* facc = ws + WS_F;
    float* ncnt = ws + WS_NCOUNT;
    float* uh   = ws + WS_UH;
    float* sk   = ws + WS_SK;
    float* Bc   = ws + WS_BC;
    float* psb  = ws + WS_PSB;
    float* pr   = ws + WS_PR;
    float* expv = ws + WS_EXPV;
    float* corr = ws + WS_CORR;

    hipMemsetAsync(facc, 0, (25600 + 200)*sizeof(float), stream);
    hipLaunchKernelGGL(k_norm_protos, dim3(208), dim3(64), 0, stream, protos, pn, phi, plo);
    hipLaunchKernelGGL(k_main, dim3(2048), dim3(256), 0, stream,
                       feat, gt, phi, plo, fg, fb, mg, mb, out_seg, plog, expv, psb, corr);
    hipLaunchKernelGGL(k_reduce_sB, dim3(40), dim3(256), 0, stream, psb, sk, Bc);
    for (int it = 1; it <= 3; ++it) {
        hipLaunchKernelGGL(k_row, dim3(1024), dim3(256), 0, stream, it, gt, expv, uh, sk, Bc, pr);
        hipLaunchKernelGGL(k_reduce_u, dim3(200), dim3(256), 0, stream, it, pr, uh);
    }
    hipLaunchKernelGGL(k_finalize, dim3(4096), dim3(256), 0, stream,
                       feat, gt, fg, fb, expv, uh + 400, corr, ptarget, facc, ncnt);
    hipLaunchKernelGGL(k_proto_update, dim3(200), dim3(64), 0, stream, facc, ncnt, pn, newp);
}

// Round 3
// 316.219 us; speedup vs baseline: 1.7767x; 1.3610x over previous
//
#include <hip/hip_runtime.h>
#include <hip/hip_bf16.h>

#define NPTS 262144
#define DIM  128
#define KC   20
#define MP   10
#define LNEPS 1e-5f
#define EPSI  0.05f
#define CCAP  65536

typedef _Float16 half8 __attribute__((ext_vector_type(8)));
typedef float f32x4 __attribute__((ext_vector_type(4)));

union H8U4 { half8 h; uint4 u; };

// workspace layout (float offsets)
#define WS_PN     0          // 25600 normalized protos f32
#define WS_PHI    25600      // 13312 floats (208x128 f16 hi)
#define WS_PLO    38912      // 13312 floats (f16 lo)
#define WS_F      52224      // 25600 f accumulator
#define WS_NCOUNT 77824      // 200
#define WS_CCNT   78024      // 8 (int counter + pad)
#define WS_UH     78032      // 600 u history (3 x 200)
#define WS_SK     78632      // 20
#define WS_BC     78652      // 20
#define WS_PSB    78672      // 40*2048
#define WS_PR     160592     // 200*1024
#define WS_EXPV   365392     // N*12 (10 + 2 pad)
#define WS_CORR   3511120    // N
#define WS_CIDX   3773264    // 65536 ints
// total 3838800 floats = 14.7 MB

__device__ __forceinline__ half8 lds_h8(const uint4* p) {
    return *reinterpret_cast<const half8*>(p);
}

// ---- normalize prototypes, emit f32 + f16 hi/lo (rows 200..207 zero-padded)
__global__ __launch_bounds__(64) void k_norm_protos(
    const float* __restrict__ pr, float* __restrict__ pn,
    _Float16* __restrict__ phi, _Float16* __restrict__ plo)
{
    int j = blockIdx.x, l = threadIdx.x;
    if (j < 200) {
        float x0 = pr[(size_t)j*128 + l], x1 = pr[(size_t)j*128 + 64 + l];
        float ss = x0*x0 + x1*x1;
        #pragma unroll
        for (int off = 32; off > 0; off >>= 1) ss += __shfl_xor(ss, off);
        float dn = fmaxf(sqrtf(ss), 1e-12f);
        float y0 = x0/dn, y1 = x1/dn;
        pn[(size_t)j*128 + l]      = y0;
        pn[(size_t)j*128 + 64 + l] = y1;
        _Float16 h0 = (_Float16)y0, h1 = (_Float16)y1;
        phi[(size_t)j*128 + l]      = h0;
        phi[(size_t)j*128 + 64 + l] = h1;
        plo[(size_t)j*128 + l]      = (_Float16)(y0 - (float)h0);
        plo[(size_t)j*128 + 64 + l] = (_Float16)(y1 - (float)h1);
    } else {
        phi[(size_t)j*128 + l] = (_Float16)0.f;  phi[(size_t)j*128 + 64 + l] = (_Float16)0.f;
        plo[(size_t)j*128 + l] = (_Float16)0.f;  plo[(size_t)j*128 + 64 + l] = (_Float16)0.f;
    }
}

// ---- main fused kernel. Block = 128 points, 4 waves.
//  A fragments in regs; B double-buffered in LDS per 16-col tile.
__global__ __launch_bounds__(256, 2) void k_main(
    const float* __restrict__ feat, const int* __restrict__ gt,
    const _Float16* __restrict__ phi, const _Float16* __restrict__ plo,
    const float* __restrict__ fg, const float* __restrict__ fb,
    const float* __restrict__ mg, const float* __restrict__ mb,
    float* __restrict__ out_seg, float* __restrict__ plog,
    float* __restrict__ expv, float* __restrict__ psb, float* __restrict__ corr,
    int* __restrict__ cidx, int* __restrict__ ccnt)
{
    __shared__ __align__(16) char smemraw[65536];
    __shared__ float sumS[128];
    __shared__ int   gtS[128];
    float4* sf4 = (float4*)smemraw;               // [128][32] f32 staging (slot^(row&15))
    uint4*  aHi = (uint4*)smemraw;                // [128][16] f16 hi
    uint4*  aLo = (uint4*)(smemraw + 32768);      // [128][16] f16 lo
    uint4*  bbuf = (uint4*)smemraw;               // [2][2][16][16] B tiles (16KB)
    float*  llds = (float*)smemraw;               // [64][210] logits staging (epilogue)

    const int t = threadIdx.x, blk = blockIdx.x;
    const int w = t >> 6, lane = t & 63;
    const int l15 = lane & 15, l4 = lane >> 4;

    // ---- prefetch B tile 0 (independent of everything)
    const uint4* phi4 = (const uint4*)phi;
    const uint4* plo4 = (const uint4*)plo;
    const int brow = t >> 4, bs = t & 15, bws = bs ^ brow;
    uint4 bsh[2], bsl[2];
    bsh[0] = phi4[(size_t)brow*16 + bs];
    bsl[0] = plo4[(size_t)brow*16 + bs];

    // ---- stage feat f32 (coalesced)
    {
        const float4* gfeat = (const float4*)feat + (size_t)blk*4096;
        #pragma unroll
        for (int ii = 0; ii < 16; ++ii) {
            int idx = ii*256 + t, row = idx >> 5, s = idx & 31;
            sf4[row*32 + (s ^ (row & 15))] = gfeat[idx];
        }
    }
    __syncthreads();

    // ---- LayerNorm + l2n, 2 threads/row, then f16 hi/lo to LDS
    {
        const int p = t >> 1, hsub = t & 1, sw = p & 15;
        float4 r[16];
        float s0 = 0.f;
        #pragma unroll
        for (int q = 0; q < 16; ++q) {
            float4 v = sf4[p*32 + ((hsub*16 + q) ^ sw)];
            s0 += v.x + v.y + v.z + v.w;
        }
        s0 += __shfl_xor(s0, 1);
        float mean = s0 * (1.f/128.f);
        float s1 = 0.f;
        #pragma unroll
        for (int q = 0; q < 16; ++q) {
            float4 v = sf4[p*32 + ((hsub*16 + q) ^ sw)];
            float a = v.x-mean, b = v.y-mean, c = v.z-mean, d = v.w-mean;
            s1 += a*a + b*b + c*c + d*d;
        }
        s1 += __shfl_xor(s1, 1);
        float rstd = rsqrtf(s1 * (1.f/128.f) + LNEPS);
        const float4* fg4 = (const float4*)fg;
        const float4* fb4 = (const float4*)fb;
        float s2 = 0.f;
        #pragma unroll
        for (int q = 0; q < 16; ++q) {
            int sl = hsub*16 + q;
            float4 v = sf4[p*32 + (sl ^ sw)];
            float4 g = fg4[sl], bb = fb4[sl];
            v.x = (v.x-mean)*rstd*g.x + bb.x;
            v.y = (v.y-mean)*rstd*g.y + bb.y;
            v.z = (v.z-mean)*rstd*g.z + bb.z;
            v.w = (v.w-mean)*rstd*g.w + bb.w;
            r[q] = v;
            s2 += v.x*v.x + v.y*v.y + v.z*v.z + v.w*v.w;
        }
        s2 += __shfl_xor(s2, 1);
        float rl2 = 1.f / fmaxf(sqrtf(s2), 1e-12f);
        #pragma unroll
        for (int q = 0; q < 16; ++q) { r[q].x *= rl2; r[q].y *= rl2; r[q].z *= rl2; r[q].w *= rl2; }

        __syncthreads();   // all f32 reads complete before overwriting with f16

        #pragma unroll
        for (int q = 0; q < 8; ++q) {
            float4 va = r[2*q], vb = r[2*q+1];
            H8U4 h, lo;
            h.h[0]=(_Float16)va.x; h.h[1]=(_Float16)va.y; h.h[2]=(_Float16)va.z; h.h[3]=(_Float16)va.w;
            h.h[4]=(_Float16)vb.x; h.h[5]=(_Float16)vb.y; h.h[6]=(_Float16)vb.z; h.h[7]=(_Float16)vb.w;
            lo.h[0]=(_Float16)(va.x-(float)h.h[0]); lo.h[1]=(_Float16)(va.y-(float)h.h[1]);
            lo.h[2]=(_Float16)(va.z-(float)h.h[2]); lo.h[3]=(_Float16)(va.w-(float)h.h[3]);
            lo.h[4]=(_Float16)(vb.x-(float)h.h[4]); lo.h[5]=(_Float16)(vb.y-(float)h.h[5]);
            lo.h[6]=(_Float16)(vb.z-(float)h.h[6]); lo.h[7]=(_Float16)(vb.w-(float)h.h[7]);
            int slot = hsub*8 + q;
            aHi[p*16 + (slot ^ sw)] = h.u;
            aLo[p*16 + (slot ^ sw)] = lo.u;
        }
    }
    __syncthreads();

    // ---- A fragments -> registers (64 VGPR), then LDS A dies
    half8 fah[2][4], fal[2][4];
    #pragma unroll
    for (int mt = 0; mt < 2; ++mt)
        #pragma unroll
        for (int kst = 0; kst < 4; ++kst) {
            int arow = w*32 + mt*16 + l15;
            int sl = (kst*4 + l4) ^ l15;
            fah[mt][kst] = lds_h8(&aHi[arow*16 + sl]);
            fal[mt][kst] = lds_h8(&aLo[arow*16 + sl]);
        }
    __syncthreads();   // frag reads done before B buf overwrites aHi region

    // ---- B double-buffered tile loop
    bbuf[brow*16 + bws]       = bsh[0];
    bbuf[256 + brow*16 + bws] = bsl[0];
    bsh[1] = phi4[(size_t)(16 + brow)*16 + bs];
    bsl[1] = plo4[(size_t)(16 + brow)*16 + bs];

    f32x4 acc[2][13];
    #pragma unroll
    for (int mt = 0; mt < 2; ++mt)
        #pragma unroll
        for (int nt = 0; nt < 13; ++nt)
            acc[mt][nt] = (f32x4){0.f,0.f,0.f,0.f};

    #pragma unroll
    for (int nt = 0; nt < 13; ++nt) {
        __syncthreads();       // buf[nt&1] writes visible
        const uint4* bb = bbuf + (nt & 1)*512;
        #pragma unroll
        for (int kst = 0; kst < 4; ++kst) {
            int sl = (kst*4 + l4) ^ l15;
            half8 bh = lds_h8(bb + l15*16 + sl);
            half8 bl = lds_h8(bb + 256 + l15*16 + sl);
            acc[0][nt] = __builtin_amdgcn_mfma_f32_16x16x32_f16(fah[0][kst], bh, acc[0][nt], 0,0,0);
            acc[0][nt] = __builtin_amdgcn_mfma_f32_16x16x32_f16(fal[0][kst], bh, acc[0][nt], 0,0,0);
            acc[0][nt] = __builtin_amdgcn_mfma_f32_16x16x32_f16(fah[0][kst], bl, acc[0][nt], 0,0,0);
            acc[0][nt] = __builtin_amdgcn_mfma_f32_16x16x32_f16(fal[0][kst], bl, acc[0][nt], 0,0,0);
            acc[1][nt] = __builtin_amdgcn_mfma_f32_16x16x32_f16(fah[1][kst], bh, acc[1][nt], 0,0,0);
            acc[1][nt] = __builtin_amdgcn_mfma_f32_16x16x32_f16(fal[1][kst], bh, acc[1][nt], 0,0,0);
            acc[1][nt] = __builtin_amdgcn_mfma_f32_16x16x32_f16(fah[1][kst], bl, acc[1][nt], 0,0,0);
            acc[1][nt] = __builtin_amdgcn_mfma_f32_16x16x32_f16(fal[1][kst], bl, acc[1][nt], 0,0,0);
        }
        if (nt < 12) {
            int nb = (nt + 1) & 1;
            bbuf[nb*512 + brow*16 + bws]       = bsh[nb];   // write tile nt+1
            bbuf[nb*512 + 256 + brow*16 + bws] = bsl[nb];
            if (nt < 11) {
                bsh[nt & 1] = phi4[(size_t)((nt+2)*16 + brow)*16 + bs];   // load tile nt+2
                bsl[nt & 1] = plo4[(size_t)((nt+2)*16 + brow)*16 + bs];
            }
        }
    }

    // ---- write plog directly from acc (64B segments per quarter-wave)
    #pragma unroll
    for (int mt = 0; mt < 2; ++mt)
        #pragma unroll
        for (int nt = 0; nt < 13; ++nt)
            #pragma unroll
            for (int rr = 0; rr < 4; ++rr)
                if (nt < 12 || l15 < 8)
                    plog[(size_t)(blk*128 + w*32 + mt*16 + l4*4 + rr)*200 + nt*16 + l15]
                        = acc[mt][nt][rr];

    // ---- two-pass epilogue via LDS logits staging
    #pragma unroll
    for (int pass = 0; pass < 2; ++pass) {
        __syncthreads();
        #pragma unroll
        for (int nt = 0; nt < 13; ++nt)
            #pragma unroll
            for (int rr = 0; rr < 4; ++rr) {
                int row = w*16 + l4*4 + rr;
                int col = nt*16 + l15;
                if (col < 200) llds[row*210 + col] = acc[pass][nt][rr];
            }
        __syncthreads();
        const int q = t >> 2, sub = t & 3;
        const int bp = (q >> 4)*32 + pass*16 + (q & 15);
        const int n = blk*128 + bp;
        float ml[5];
        #pragma unroll
        for (int kk = 0; kk < 5; ++kk) {
            int k = sub*5 + kk;
            float mx = llds[q*210 + k*10];
            #pragma unroll
            for (int m = 1; m < 10; ++m) mx = fmaxf(mx, llds[q*210 + k*10 + m]);
            ml[kk] = mx;
        }
        float s0 = ml[0]+ml[1]+ml[2]+ml[3]+ml[4];
        s0 += __shfl_xor(s0,1); s0 += __shfl_xor(s0,2);
        float mean = s0 / 20.f;
        float s1 = 0.f;
        #pragma unroll
        for (int kk = 0; kk < 5; ++kk) { float d = ml[kk]-mean; s1 += d*d; }
        s1 += __shfl_xor(s1,1); s1 += __shfl_xor(s1,2);
        float rstd = rsqrtf(s1 / 20.f + LNEPS);
        float bv = -1e30f; int bk = 0;
        #pragma unroll
        for (int kk = 0; kk < 5; ++kk) {
            int k = sub*5 + kk;
            float y = (ml[kk]-mean)*rstd*mg[k] + mb[k];
            out_seg[(size_t)n*20 + k] = y;
            if (y > bv) { bv = y; bk = k; }
        }
        #pragma unroll
        for (int off = 1; off <= 2; off <<= 1) {   // first-max-wins merge
            float ov = __shfl_xor(bv, off);
            int   ok = __shfl_xor(bk, off);
            if (ov > bv || (ov == bv && ok < bk)) { bv = ov; bk = ok; }
        }
        int g = gt[n];
        if (sub == 0) {
            bool isc = (bk == g);
            corr[n] = isc ? 1.f : 0.f;
            if (isc) {
                int slot = atomicAdd(ccnt, 1);
                if (slot < CCAP) cidx[slot] = n;
            }
            float se = 0.f;
            #pragma unroll
            for (int m = 0; m < 10; ++m) {
                float e = expf(llds[q*210 + g*10 + m] / EPSI);
                expv[(size_t)n*12 + m] = e;
                se += e;
            }
            expv[(size_t)n*12 + 10] = 0.f;
            expv[(size_t)n*12 + 11] = 0.f;
            sumS[pass*64 + q] = se;
            gtS[pass*64 + q] = g;
        }
    }
    __syncthreads();
    // ---- deterministic per-block class partials
    if (t < 20) {
        float cnt = 0.f, s = 0.f;
        for (int i = 0; i < 128; ++i)
            if (gtS[i] == t) { cnt += 1.f; s += sumS[i]; }
        psb[(size_t)t*2048 + blk]      = cnt;
        psb[(size_t)(20+t)*2048 + blk] = s;
    }
}

// ---- reduce class partials -> Bc, sk (deterministic tree)
__global__ __launch_bounds__(256) void k_reduce_sB(
    const float* __restrict__ psb, float* __restrict__ sk, float* __restrict__ Bc)
{
    __shared__ float red[256];
    int t = threadIdx.x, rrow = blockIdx.x;
    float s = 0.f;
    #pragma unroll
    for (int i = 0; i < 8; ++i) s += psb[(size_t)rrow*2048 + i*256 + t];
    red[t] = s; __syncthreads();
    for (int off = 128; off > 0; off >>= 1) { if (t < off) red[t] += red[t+off]; __syncthreads(); }
    if (t == 0) { if (rrow < 20) Bc[rrow] = red[0]; else sk[rrow-20] = red[0]; }
}

// ---- sinkhorn row pass with fused v-chain (iter = 1,2,3)
__global__ __launch_bounds__(256) void k_row(int iter,
    const int* __restrict__ gt, const float* __restrict__ expv,
    const float* __restrict__ uh, const float* __restrict__ sk,
    const float* __restrict__ Bc, float* __restrict__ pr)
{
    __shared__ float prodS[256*10];
    __shared__ int gtS[256];
    int t = threadIdx.x, b = blockIdx.x;
    int n = b*256 + t;
    int g = gt[n];
    float e[10];
    {
        const float4* e4 = (const float4*)(expv + (size_t)n*12);
        float4 ea = e4[0], eb = e4[1], ec = e4[2];
        e[0]=ea.x; e[1]=ea.y; e[2]=ea.z; e[3]=ea.w;
        e[4]=eb.x; e[5]=eb.y; e[6]=eb.z; e[7]=eb.w;
        e[8]=ec.x; e[9]=ec.y;
    }
    float skg = sk[g];
    float v = (skg > 0.f) ? 1.f/skg : 1.f;
    float B = Bc[g];
    float Bs = (B > 0.f) ? B : 1.f;
    for (int c = 1; c < iter; ++c) {
        const float* uc = uh + (c-1)*200 + g*10;
        float sc = 0.f;
        #pragma unroll
        for (int m = 0; m < 10; ++m) sc += e[m]*uc[m];
        v = (sc > 0.f) ? 1.f/(Bs*sc) : v/Bs;
    }
    #pragma unroll
    for (int m = 0; m < 10; ++m) prodS[t*10+m] = e[m]*v;
    gtS[t] = g;
    __syncthreads();
    if (t < 200) {
        int kk = t / 10, mm = t % 10;
        float acc = 0.f;
        for (int i = 0; i < 256; ++i)
            if (gtS[i] == kk) acc += prodS[i*10+mm];
        pr[(size_t)t*1024 + b] = acc;
    }
}

// ---- row partials -> u_hist[iter] (faithful rs>0 guard), deterministic
__global__ __launch_bounds__(256) void k_reduce_u(int iter,
    const float* __restrict__ pr, float* __restrict__ uh)
{
    __shared__ float red[256];
    int t = threadIdx.x, j = blockIdx.x;
    float s = 0.f;
    #pragma unroll
    for (int i = 0; i < 4; ++i) s += pr[(size_t)j*1024 + i*256 + t];
    red[t] = s; __syncthreads();
    for (int off = 128; off > 0; off >>= 1) { if (t < off) red[t] += red[t+off]; __syncthreads(); }
    if (t == 0) {
        float S = red[0];
        float uprev = (iter == 1) ? 1.f : uh[(iter-2)*200 + j];
        uh[(iter-1)*200 + j] = (S > 0.f) ? 1.f/(10.f*S) : uprev*0.1f;
    }
}

// ---- per-point proto assignment: ptarget + ncount
__global__ __launch_bounds__(256) void k_assign(
    const int* __restrict__ gt, const float* __restrict__ expv,
    const float* __restrict__ u, const float* __restrict__ corr,
    float* __restrict__ ptarget, float* __restrict__ ncount)
{
    int n = blockIdx.x*256 + threadIdx.x;
    int g = gt[n];
    const float* uk = u + g*10;
    float bv = -1e30f; int idx = 0;
    #pragma unroll
    for (int m = 0; m < 10; ++m) {
        float pm = expv[(size_t)n*12 + m] * uk[m];
        if (pm > bv) { bv = pm; idx = m; }
    }
    ptarget[n] = (float)(idx + 10*g);
    if (corr[n] != 0.f) atomicAdd(&ncount[g*10+idx], 1.f);
}

// ---- f accumulation: one wave per correct point, recompute _c exactly (f32)
__global__ __launch_bounds__(256) void k_accum(
    const float* __restrict__ feat, const int* __restrict__ gt,
    const float* __restrict__ fg, const float* __restrict__ fb,
    const float* __restrict__ expv, const float* __restrict__ u,
    const int* __restrict__ cidx, const int* __restrict__ ccnt,
    float* __restrict__ facc)
{
    int wid = (blockIdx.x*256 + threadIdx.x) >> 6;
    int lane = threadIdx.x & 63;
    int cnt = *ccnt; if (cnt > CCAP) cnt = CCAP;
    for (int i = wid; i < cnt; i += 1024) {
        int n = cidx[i];
        float x0 = feat[(size_t)n*128 + lane], x1 = feat[(size_t)n*128 + 64 + lane];
        float s = x0 + x1;
        #pragma unroll
        for (int off = 32; off > 0; off >>= 1) s += __shfl_xor(s, off);
        float mean = s * (1.f/128.f);
        float d0 = x0 - mean, d1 = x1 - mean;
        float s2 = d0*d0 + d1*d1;
        #pragma unroll
        for (int off = 32; off > 0; off >>= 1) s2 += __shfl_xor(s2, off);
        float rstd = rsqrtf(s2 * (1.f/128.f) + LNEPS);
        float y0 = d0*rstd*fg[lane] + fb[lane];
        float y1 = d1*rstd*fg[64+lane] + fb[64+lane];
        float s3 = y0*y0 + y1*y1;
        #pragma unroll
        for (int off = 32; off > 0; off >>= 1) s3 += __shfl_xor(s3, off);
        float rl2 = 1.f / fmaxf(sqrtf(s3), 1e-12f);
        float c0 = y0*rl2, c1 = y1*rl2;
        int g = gt[n];
        const float* uk = u + g*10;
        float bv = -1e30f; int idx = 0;
        #pragma unroll
        for (int m = 0; m < 10; ++m) {
            float pm = expv[(size_t)n*12 + m] * uk[m];
            if (pm > bv) { bv = pm; idx = m; }
        }
        float* frow = facc + (size_t)(g*10+idx)*128;
        atomicAdd(&frow[lane], c0);
        atomicAdd(&frow[64+lane], c1);
    }
}

// ---- momentum update + renormalize prototypes
__global__ __launch_bounds__(64) void k_proto_update(
    const float* __restrict__ facc, const float* __restrict__ ncount,
    const float* __restrict__ pn, float* __restrict__ outp)
{
    const float OMG = (float)(1.0 - 0.99);
    int j = blockIdx.x, l = threadIdx.x;
    float f0 = facc[(size_t)j*128+l], f1 = facc[(size_t)j*128+64+l];
    float ss = f0*f0 + f1*f1;
    #pragma unroll
    for (int off = 32; off > 0; off >>= 1) ss += __shfl_xor(ss, off);
    float fl2 = fmaxf(sqrtf(ss), 1e-12f);
    float fn0 = f0/fl2, fn1 = f1/fl2;
    float p0 = pn[(size_t)j*128+l], p1 = pn[(size_t)j*128+64+l];
    float u0 = 0.99f*p0 + OMG*fn0, u1 = 0.99f*p1 + OMG*fn1;
    bool ok = ncount[j] > 0.f;
    float s0 = ok ? u0 : p0, s1 = ok ? u1 : p1;
    float ss2 = s0*s0 + s1*s1;
    #pragma unroll
    for (int off = 32; off > 0; off >>= 1) ss2 += __shfl_xor(ss2, off);
    float l2 = fmaxf(sqrtf(ss2), 1e-12f);
    outp[(size_t)j*128+l]      = s0/l2;
    outp[(size_t)j*128+64+l]   = s1/l2;
}

extern "C" void kernel_launch(void* const* d_in, const int* in_sizes, int n_in,
                              void* d_out, int out_size, void* d_ws, size_t ws_size,
                              hipStream_t stream)
{
    const float* feat   = (const float*)d_in[0];
    const int*   gt     = (const int*)  d_in[1];
    const float* protos = (const float*)d_in[2];
    const float* fg     = (const float*)d_in[3];
    const float* fb     = (const float*)d_in[4];
    const float* mg     = (const float*)d_in[5];
    const float* mb     = (const float*)d_in[6];

    float* out      = (float*)d_out;
    float* out_seg  = out;
    float* plog     = out + (size_t)NPTS*20;
    float* ptarget  = out + (size_t)NPTS*220;
    float* newp     = out + (size_t)NPTS*221;

    float* ws   = (float*)d_ws;
    float* pn   = ws + WS_PN;
    _Float16* phi = (_Float16*)(ws + WS_PHI);
    _Float16* plo = (_Float16*)(ws + WS_PLO);
    float* facc = ws + WS_F;
    float* ncnt = ws + WS_NCOUNT;
    int*   ccnt = (int*)(ws + WS_CCNT);
    float* uh   = ws + WS_UH;
    float* sk   = ws + WS_SK;
    float* Bc   = ws + WS_BC;
    float* psb  = ws + WS_PSB;
    float* pr   = ws + WS_PR;
    float* expv = ws + WS_EXPV;
    float* corr = ws + WS_CORR;
    int*   cidx = (int*)(ws + WS_CIDX);

    // zero facc + ncount + ccnt (contiguous)
    hipMemsetAsync(facc, 0, (25600 + 200 + 8)*sizeof(float), stream);
    hipLaunchKernelGGL(k_norm_protos, dim3(208), dim3(64), 0, stream, protos, pn, phi, plo);
    hipLaunchKernelGGL(k_main, dim3(2048), dim3(256), 0, stream,
                       feat, gt, phi, plo, fg, fb, mg, mb, out_seg, plog, expv, psb, corr,
                       cidx, ccnt);
    hipLaunchKernelGGL(k_reduce_sB, dim3(40), dim3(256), 0, stream, psb, sk, Bc);
    for (int it = 1; it <= 3; ++it) {
        hipLaunchKernelGGL(k_row, dim3(1024), dim3(256), 0, stream, it, gt, expv, uh, sk, Bc, pr);
        hipLaunchKernelGGL(k_reduce_u, dim3(200), dim3(256), 0, stream, it, pr, uh);
    }
    hipLaunchKernelGGL(k_assign, dim3(1024), dim3(256), 0, stream,
                       gt, expv, uh + 400, corr, ptarget, ncnt);
    hipLaunchKernelGGL(k_accum, dim3(256), dim3(256), 0, stream,
                       feat, gt, fg, fb, expv, uh + 400, cidx, ccnt, facc);
    hipLaunchKernelGGL(k_proto_update, dim3(200), dim3(64), 0, stream, facc, ncnt, pn, newp);
}